// Round 2
// baseline (8529.464 us; speedup 1.0000x reference)
//
#include <hip/hip_runtime.h>

#define QD 8
#define BLK 256

__device__ __forceinline__ void load8(const float* __restrict__ p, float v[QD]) {
    const float4* p4 = reinterpret_cast<const float4*>(p);
    float4 a = p4[0], b = p4[1];
    v[0]=a.x; v[1]=a.y; v[2]=a.z; v[3]=a.w;
    v[4]=b.x; v[5]=b.y; v[6]=b.z; v[7]=b.w;
}

__device__ __forceinline__ void store8(float* __restrict__ p, const float v[QD]) {
    float4* p4 = reinterpret_cast<float4*>(p);
    float4 a = {v[0],v[1],v[2],v[3]};
    float4 b = {v[4],v[5],v[6],v[7]};
    p4[0]=a; p4[1]=b;
}

__device__ __forceinline__ void softmax8(const float v[QD], float o[QD]) {
    float m = v[0];
    #pragma unroll
    for (int i=1;i<QD;i++) m = fmaxf(m, v[i]);
    float s = 0.f;
    #pragma unroll
    for (int i=0;i<QD;i++){ o[i] = expf(v[i]-m); s += o[i]; }
    float inv = 1.0f/s;
    #pragma unroll
    for (int i=0;i<QD;i++) o[i] *= inv;
}

// psi = softmax(psi0) row-wise over 2E rows
__global__ void init_kernel(const float* __restrict__ psi0, float* __restrict__ psi, int twoE) {
    int e = blockIdx.x*BLK + threadIdx.x;
    if (e >= twoE) return;
    float v[QD], o[QD];
    load8(psi0 + (size_t)e*QD, v);
    softmax8(v, o);
    store8(psi + (size_t)e*QD, o);
}

// node_sum[dst[e]] += log1p(w*psi[e]); also zero h_acc for the following h-kernel
__global__ void scatter_kernel(const float* __restrict__ psi,
                               const int* __restrict__ ei,   // flat edge_index, 2E ints
                               float* __restrict__ ns,
                               float* __restrict__ h_acc,
                               const float* __restrict__ beta,
                               int E, int twoE) {
    int e = blockIdx.x*BLK + threadIdx.x;
    if (blockIdx.x == 0 && threadIdx.x < QD) h_acc[threadIdx.x] = 0.0f;
    if (e >= twoE) return;
    float b = beta[0];
    float w = expf(b) - 1.0f;
    int r = (e < E) ? (e + E) : (e - E);
    int d = ei[r];                      // dst[e] == flat edge_index[rev(e)]
    float v[QD];
    load8(psi + (size_t)e*QD, v);
    float* nrow = ns + (size_t)d*QD;
    #pragma unroll
    for (int q=0;q<QD;q++) unsafeAtomicAdd(nrow + q, log1pf(w*v[q]));
}

// h_acc[q] += sum_n softmax(node_sum[n])[q]; also zero the OTHER node_sum buffer
__global__ void h_kernel(const float* __restrict__ ns,
                         float* __restrict__ h_acc,
                         float* __restrict__ ns_other,
                         int N) {
    int n = blockIdx.x*BLK + threadIdx.x;
    float m8[QD];
    #pragma unroll
    for (int q=0;q<QD;q++) m8[q] = 0.0f;
    if (n < N) {
        float v[QD];
        load8(ns + (size_t)n*QD, v);
        softmax8(v, m8);
    }
    // wave-level (64-lane) reduction per q, then one atomic per wave per q
    #pragma unroll
    for (int q=0;q<QD;q++) {
        float v = m8[q];
        #pragma unroll
        for (int off=32; off; off >>= 1) v += __shfl_down(v, off);
        if ((threadIdx.x & 63) == 0) unsafeAtomicAdd(&h_acc[q], v);
    }
    // zero the other node_sum buffer for the next iteration
    int total = N * QD;
    for (int i = blockIdx.x*BLK + threadIdx.x; i < total; i += gridDim.x*BLK)
        ns_other[i] = 0.0f;
}

// psi_out[e] = softmax( ns[src[e]] - log1p(w*psi_in[rev(e)]) - (b/N)*h_acc )
__global__ void update_kernel(const float* __restrict__ psi_in,
                              float* __restrict__ psi_out,
                              const int* __restrict__ ei,
                              const float* __restrict__ ns,
                              const float* __restrict__ h_acc,
                              const float* __restrict__ beta,
                              int E, int twoE, float invN) {
    int e = blockIdx.x*BLK + threadIdx.x;
    if (e >= twoE) return;
    float b = beta[0];
    float w = expf(b) - 1.0f;
    float hb = b * invN;
    int s = ei[e];                       // src[e]
    int r = (e < E) ? (e + E) : (e - E); // rev(e)
    float nsv[QD], pr[QD], lg[QD], o[QD];
    load8(ns + (size_t)s*QD, nsv);
    load8(psi_in + (size_t)r*QD, pr);
    #pragma unroll
    for (int q=0;q<QD;q++)
        lg[q] = nsv[q] - log1pf(w*pr[q]) - hb*h_acc[q];
    softmax8(lg, o);
    store8(psi_out + (size_t)e*QD, o);
}

// marginal = softmax(node_sum) row-wise -> out
__global__ void marginal_kernel(const float* __restrict__ ns, float* __restrict__ out, int N) {
    int n = blockIdx.x*BLK + threadIdx.x;
    if (n >= N) return;
    float v[QD], o[QD];
    load8(ns + (size_t)n*QD, v);
    softmax8(v, o);
    store8(out + (size_t)n*QD, o);
}

extern "C" void kernel_launch(void* const* d_in, const int* in_sizes, int n_in,
                              void* d_out, int out_size, void* d_ws, size_t ws_size,
                              hipStream_t stream) {
    const int*   ei   = (const int*)d_in[0];    // (2,E) flat: [0..E)=src_u, [E..2E)=dst_u
    const float* psi0 = (const float*)d_in[1];  // (2E, Q)
    const float* beta = (const float*)d_in[2];  // (1,)

    int twoE = in_sizes[0];          // 2E
    int E    = twoE / 2;
    int Q    = in_sizes[1] / twoE;   // = 8
    int N    = (out_size - in_sizes[1]) / Q;

    float* out = (float*)d_out;
    float* P0  = out;                              // psi buffer 0 (= message_map slot)
    float* P1  = (float*)d_ws;                     // psi buffer 1
    float* ns0 = P1 + (size_t)twoE * QD;           // node_sum buffer 0
    float* ns1 = ns0 + (size_t)N * QD;             // node_sum buffer 1
    float* h_acc = ns1 + (size_t)N * QD;           // 8 floats

    int egrid = (twoE + BLK - 1) / BLK;
    int ngrid = (N + BLK - 1) / BLK;
    float invN = 1.0f / (float)N;

    // zero node_sum buffer used by iteration 0
    hipMemsetAsync(ns0, 0, (size_t)N * QD * sizeof(float), stream);

    init_kernel<<<egrid, BLK, 0, stream>>>(psi0, P0, twoE);

    float* pin  = P0;
    float* pout = P1;
    for (int k = 0; k < 10; ++k) {
        float* ns  = (k & 1) ? ns1 : ns0;
        float* nso = (k & 1) ? ns0 : ns1;
        scatter_kernel<<<egrid, BLK, 0, stream>>>(pin, ei, ns, h_acc, beta, E, twoE);
        h_kernel<<<ngrid, BLK, 0, stream>>>(ns, h_acc, nso, N);
        update_kernel<<<egrid, BLK, 0, stream>>>(pin, pout, ei, ns, h_acc, beta, E, twoE, invN);
        float* t = pin; pin = pout; pout = t;
    }
    // after 10 iterations (even), psi lives in P0 == d_out (message_map done in place)

    // final node field with the final psi; ns0 was zeroed by iteration 9's h_kernel
    scatter_kernel<<<egrid, BLK, 0, stream>>>(P0, ei, ns0, h_acc, beta, E, twoE);
    marginal_kernel<<<ngrid, BLK, 0, stream>>>(ns0, out + (size_t)twoE * QD, N);
}

// Round 4
// 2247.234 us; speedup vs baseline: 3.7955x; 3.7955x over previous
//
#include <hip/hip_runtime.h>

#define QD 8
#define BLK 256

__device__ __forceinline__ void load8(const float* __restrict__ p, float v[QD]) {
    const float4* p4 = reinterpret_cast<const float4*>(p);
    float4 a = p4[0], b = p4[1];
    v[0]=a.x; v[1]=a.y; v[2]=a.z; v[3]=a.w;
    v[4]=b.x; v[5]=b.y; v[6]=b.z; v[7]=b.w;
}

__device__ __forceinline__ void store8(float* __restrict__ p, const float v[QD]) {
    float4* p4 = reinterpret_cast<float4*>(p);
    float4 a = {v[0],v[1],v[2],v[3]};
    float4 b = {v[4],v[5],v[6],v[7]};
    p4[0]=a; p4[1]=b;
}

__device__ __forceinline__ void softmax8(const float v[QD], float o[QD]) {
    float m = v[0];
    #pragma unroll
    for (int i=1;i<QD;i++) m = fmaxf(m, v[i]);
    float s = 0.f;
    #pragma unroll
    for (int i=0;i<QD;i++){ o[i] = expf(v[i]-m); s += o[i]; }
    float inv = 1.0f/s;
    #pragma unroll
    for (int i=0;i<QD;i++) o[i] *= inv;
}

// psi = softmax(psi0) row-wise over 2E rows (into d_out)
__global__ void init_kernel(const float* __restrict__ psi0, float* __restrict__ psi, int twoE) {
    int e = blockIdx.x*BLK + threadIdx.x;
    if (e >= twoE) return;
    float v[QD], o[QD];
    load8(psi0 + (size_t)e*QD, v);
    softmax8(v, o);
    store8(psi + (size_t)e*QD, o);
}

// deg[dst[e]]++ for each directed edge e; dst[e] = ei[rev(e)], rev(e)=e±E
__global__ void count_kernel(const int* __restrict__ ei, int* __restrict__ deg, int E, int twoE) {
    int e = blockIdx.x*BLK + threadIdx.x;
    if (e >= twoE) return;
    int r = (e < E) ? (e + E) : (e - E);
    atomicAdd(&deg[ei[r]], 1);
}

// single-block exclusive scan: deg -> rowstart (N+1), cursor = rowstart
__global__ void scan_kernel(const int* __restrict__ deg, int* __restrict__ rowstart,
                            int* __restrict__ cursor, int N, int twoE) {
    __shared__ int part[1024];
    int tid = threadIdx.x;
    int chunk = (N + 1023) / 1024;
    int lo = tid * chunk;
    int hi = lo + chunk; if (hi > N) hi = N; if (lo > N) lo = N;
    int s = 0;
    for (int i = lo; i < hi; ++i) s += deg[i];
    part[tid] = s;
    __syncthreads();
    for (int off = 1; off < 1024; off <<= 1) {
        int v = (tid >= off) ? part[tid - off] : 0;
        __syncthreads();
        part[tid] += v;
        __syncthreads();
    }
    int run = (tid == 0) ? 0 : part[tid - 1];
    for (int i = lo; i < hi; ++i) {
        rowstart[i] = run; cursor[i] = run; run += deg[i];
    }
    if (tid == 1023) rowstart[N] = twoE;
}

// adj[slot] = e, slot = cursor[dst[e]]++
__global__ void fill_kernel(const int* __restrict__ ei, int* __restrict__ cursor,
                            int* __restrict__ adj, int E, int twoE) {
    int e = blockIdx.x*BLK + threadIdx.x;
    if (e >= twoE) return;
    int r = (e < E) ? (e + E) : (e - E);
    int d = ei[r];
    int slot = atomicAdd(&cursor[d], 1);
    adj[slot] = e;
}

// 8 lanes per node: ns[n][q] = sum over incoming edges of log1p(w*psi[e][q]).
// Fused h: softmax across the 8 lanes -> marginal component; wave-reduce same-q
// lanes -> 8 atomics/wave into hslot (pre-zeroed per-iteration slot).
__global__ void nodesum_kernel(const float* __restrict__ psi,
                               const int* __restrict__ adj,
                               const int* __restrict__ rowstart,
                               float* __restrict__ ns,
                               float* __restrict__ hslot,
                               const float* __restrict__ beta,
                               int N) {
    int gid = blockIdx.x*BLK + threadIdx.x;
    int node = gid >> 3;
    int q = gid & 7;
    float w = expf(beta[0]) - 1.0f;
    float hc = 0.0f;
    if (node < N) {
        int s = rowstart[node], t = rowstart[node + 1];
        float acc = 0.0f;
        for (int i = s; i < t; ++i) {
            int e = adj[i];
            acc += log1pf(w * psi[(size_t)e*QD + q]);
        }
        ns[(size_t)node*QD + q] = acc;
        // softmax across the 8 lanes of this node-group
        float m = acc;
        #pragma unroll
        for (int d = 1; d < 8; d <<= 1) m = fmaxf(m, __shfl_xor(m, d, 8));
        float ex = expf(acc - m);
        float ssum = ex;
        #pragma unroll
        for (int d = 1; d < 8; d <<= 1) ssum += __shfl_xor(ssum, d, 8);
        hc = ex / ssum;          // marginal[node][q]
    }
    // reduce across lanes with the same q within the wave (xor lane bits 3,4,5)
    hc += __shfl_xor(hc, 8);
    hc += __shfl_xor(hc, 16);
    hc += __shfl_xor(hc, 32);
    if ((threadIdx.x & 63) < 8) unsafeAtomicAdd(&hslot[threadIdx.x & 7], hc);
}

// In-place pair update: thread t handles directed edges t (u->v) and t+E (v->u).
// psi[t]   = softmax( ns[u] - log1p(w*psi[t+E]) - h )
// psi[t+E] = softmax( ns[v] - log1p(w*psi[t])   - h )
__global__ void update_kernel(float* __restrict__ psi,
                              const int* __restrict__ ei,
                              const float* __restrict__ ns,
                              const float* __restrict__ hslot,
                              const float* __restrict__ beta,
                              int E, float invN) {
    int t = blockIdx.x*BLK + threadIdx.x;
    if (t >= E) return;
    float b = beta[0];
    float w = expf(b) - 1.0f;
    float hb = b * invN;
    int u = ei[t];
    int v = ei[t + E];
    float pf[QD], pr[QD], nsu[QD], nsv[QD], lg[QD], o1[QD], o2[QD], h8[QD];
    load8(psi + (size_t)t*QD, pf);
    load8(psi + ((size_t)t + E)*QD, pr);
    load8(ns + (size_t)u*QD, nsu);
    load8(ns + (size_t)v*QD, nsv);
    #pragma unroll
    for (int q = 0; q < QD; q++) h8[q] = hb * hslot[q];
    #pragma unroll
    for (int q = 0; q < QD; q++) lg[q] = nsu[q] - log1pf(w*pr[q]) - h8[q];
    softmax8(lg, o1);
    #pragma unroll
    for (int q = 0; q < QD; q++) lg[q] = nsv[q] - log1pf(w*pf[q]) - h8[q];
    softmax8(lg, o2);
    store8(psi + (size_t)t*QD, o1);
    store8(psi + ((size_t)t + E)*QD, o2);
}

// marginal = softmax(node_sum) row-wise -> out tail
__global__ void marginal_kernel(const float* __restrict__ ns, float* __restrict__ out, int N) {
    int n = blockIdx.x*BLK + threadIdx.x;
    if (n >= N) return;
    float v[QD], o[QD];
    load8(ns + (size_t)n*QD, v);
    softmax8(v, o);
    store8(out + (size_t)n*QD, o);
}

extern "C" void kernel_launch(void* const* d_in, const int* in_sizes, int n_in,
                              void* d_out, int out_size, void* d_ws, size_t ws_size,
                              hipStream_t stream) {
    const int*   ei   = (const int*)d_in[0];    // (2,E) flat: [0..E)=src_u, [E..2E)=dst_u
    const float* psi0 = (const float*)d_in[1];  // (2E, Q)
    const float* beta = (const float*)d_in[2];  // (1,)

    int twoE = in_sizes[0];
    int E    = twoE / 2;
    int N    = (out_size - in_sizes[1]) / QD;

    // workspace layout (all 16B aligned)
    char* ws = (char*)d_ws;
    float* ns       = (float*)ws;  ws += (size_t)N * QD * sizeof(float);   // 1.6 MB
    int*   deg      = (int*)ws;    ws += (size_t)N * sizeof(int);          // 200 KB
    int*   rowstart = (int*)ws;    ws += (size_t)(N + 8) * sizeof(int);    // 200 KB
    int*   cursor   = (int*)ws;    ws += (size_t)N * sizeof(int);          // 200 KB
    int*   adj      = (int*)ws;    ws += (size_t)twoE * sizeof(int);       // 6.4 MB
    float* h_acc    = (float*)ws;                                          // 11*8 floats

    int eg2 = (twoE + BLK - 1) / BLK;
    int eg1 = (E    + BLK - 1) / BLK;
    int ng  = (N    + BLK - 1) / BLK;
    int ng8 = (N*QD + BLK - 1) / BLK;
    float invN = 1.0f / (float)N;
    float* psi = (float*)d_out;

    hipMemsetAsync(deg,   0, (size_t)N * sizeof(int), stream);
    hipMemsetAsync(h_acc, 0, (size_t)11 * QD * sizeof(float), stream);

    count_kernel<<<eg2, BLK, 0, stream>>>(ei, deg, E, twoE);
    scan_kernel<<<1, 1024, 0, stream>>>(deg, rowstart, cursor, N, twoE);
    fill_kernel<<<eg2, BLK, 0, stream>>>(ei, cursor, adj, E, twoE);
    init_kernel<<<eg2, BLK, 0, stream>>>(psi0, psi, twoE);

    for (int k = 0; k < 10; ++k) {
        nodesum_kernel<<<ng8, BLK, 0, stream>>>(psi, adj, rowstart, ns, h_acc + k*QD, beta, N);
        update_kernel<<<eg1, BLK, 0, stream>>>(psi, ei, ns, h_acc + k*QD, beta, E, invN);
    }
    // final node field + marginal (h slot 10 is written but unused)
    nodesum_kernel<<<ng8, BLK, 0, stream>>>(psi, adj, rowstart, ns, h_acc + 10*QD, beta, N);
    marginal_kernel<<<ng, BLK, 0, stream>>>(ns, psi + (size_t)twoE*QD, N);
}